// Round 4
// baseline (105.453 us; speedup 1.0000x reference)
//
#include <hip/hip_runtime.h>

// HyperLinear, 2-kernel split, G intermediate eliminated algebraically:
//  setup:  blocks 0..35 : Bbp = swizzled bf16 Bb (576x256: 512 permuted fcwp_w
//                         rows + 64 c-rows), stored in MFMA B-fragment order
//                         [n_tile][k_tile][lane][8] for direct global->VGPR loads.
//          blocks 36..56: B2p = swizzled bf16 B2 (256x352:
//                         target_w|fcwe_w|fcbp_w|fcwe_b|bias_const|0), same order.
//  main:   64 blocks x 32 samples. Per block:
//            stage A-panel x cols [0,256) (fp32->bf16) + h cols + sx/1/0 cols;
//            gemm1 row-strip: per wave, 9 B-tiles (8 p-tiles + 1 c-tile) x K=256
//            with B-frags loaded directly from global; each 16-col G-tile is
//            folded into t in-register (8-lane shfl_xor butterfly weighted by h)
//            and accumulated in LDS T[32][64] (f32, G never materialized);
//            t -> bf16 A-panel cols [256,320); then gemm2 out = Apanel @ B2^T.

#define B_TOT 2048
#define NP    8
#define CIN   256
#define COUT  256
#define MID   64
#define K2    352
#define LDA2S 360

typedef short  short8  __attribute__((ext_vector_type(8)));
typedef float  floatx4 __attribute__((ext_vector_type(4)));

__device__ __forceinline__ unsigned short f2bf(float f) {
    union { float f; unsigned u; } v; v.f = f;
    unsigned r = v.u + 0x7FFFu + ((v.u >> 16) & 1u);
    return (unsigned short)(r >> 16);
}

// MFMA B-fragment swizzle: element (row, k) of a row-major [rows][K] bf16
// matrix, K = ktiles*32. Fragment layout for mfma_f32_16x16x32_bf16:
// lane = ((k>>3)&3)*16 + (row&15), elem j = k&7, tile = (row>>4)*ktiles + (k>>5).
__device__ __forceinline__ size_t bswz(int row, int k, int ktiles) {
    return ((size_t)(row >> 4) * ktiles + (k >> 5)) * 512
         + (size_t)(((((k >> 3) & 3) << 4) | (row & 15)) * 8 + (k & 7));
}

// ---------------- setup: Bbp (36 blocks) + B2p (21 blocks) ----------------
__global__ __launch_bounds__(256) void setup_kernel(
    const float* __restrict__ index,
    const float* __restrict__ fcwp_w, const float* __restrict__ fcwp_b,
    const float* __restrict__ fcwi_w, const float* __restrict__ fcwi_b,
    const float* __restrict__ target_w, const float* __restrict__ target_b,
    const float* __restrict__ fcwe_w, const float* __restrict__ fcwe_b,
    const float* __restrict__ fcbp_w, const float* __restrict__ fcbp_b,
    const float* __restrict__ fcbi_w, const float* __restrict__ fcbi_b,
    unsigned short* __restrict__ Bbp,        // 36*8*512 elems
    unsigned short* __restrict__ B2p)        // 16*11*512 elems
{
    __shared__ unsigned short Lt[64][68];
    const int blk = blockIdx.x, tid = threadIdx.x;

    if (blk < 32) {
        // Bb[n][k] = bf16(fcwp_w[k*512+n]); 64x64 tile transpose via LDS
        const int i0 = (blk >> 3) * 64, n0 = (blk & 7) * 64;
        const int r = tid >> 4, c4 = (tid & 15) * 4;
        #pragma unroll
        for (int k = 0; k < 4; ++k) {
            int ii = r + k * 16;
            float4 v = *(const float4*)(fcwp_w + (size_t)(i0 + ii) * 512 + n0 + c4);
            Lt[c4 + 0][ii] = f2bf(v.x); Lt[c4 + 1][ii] = f2bf(v.y);
            Lt[c4 + 2][ii] = f2bf(v.z); Lt[c4 + 3][ii] = f2bf(v.w);
        }
        __syncthreads();
        const int nn = tid >> 2, ic0 = (tid & 3) * 16;
        #pragma unroll
        for (int k = 0; k < 4; ++k) {
            int ic = ic0 + k * 4;
            ushort4 o4;
            o4.x = Lt[nn][ic]; o4.y = Lt[nn][ic + 1];
            o4.z = Lt[nn][ic + 2]; o4.w = Lt[nn][ic + 3];
            *(ushort4*)&Bbp[bswz(n0 + nn, i0 + ic, 8)] = o4;
        }
    } else if (blk < 36) {
        // c rows: Bb[512+m][k], e = k*64+m
        const int i0 = (blk - 32) * 64;
        const float x0 = index[0], x1 = index[1], x2 = index[2], x3 = index[3];
        const int r = tid >> 4, c4 = (tid & 15) * 4;
        #pragma unroll
        for (int k = 0; k < 4; ++k) {
            int ii = r + k * 16;
            int e = (i0 + ii) * 64 + c4;
            float4 pb = *(const float4*)(fcwp_b + e);
            float4 ib = *(const float4*)(fcwi_b + e);
            float pbv[4] = {pb.x, pb.y, pb.z, pb.w};
            float ibv[4] = {ib.x, ib.y, ib.z, ib.w};
            #pragma unroll
            for (int j = 0; j < 4; ++j) {
                float4 wv = *(const float4*)(fcwi_w + (size_t)(e + j) * 4);
                Lt[c4 + j][ii] = f2bf(pbv[j] + ibv[j]
                    + x0 * wv.x + x1 * wv.y + x2 * wv.z + x3 * wv.w);
            }
        }
        __syncthreads();
        const int mm = tid >> 2, ic0 = (tid & 3) * 16;
        #pragma unroll
        for (int k = 0; k < 4; ++k) {
            int ic = ic0 + k * 4;
            ushort4 o4;
            o4.x = Lt[mm][ic]; o4.y = Lt[mm][ic + 1];
            o4.z = Lt[mm][ic + 2]; o4.w = Lt[mm][ic + 3];
            *(ushort4*)&Bbp[bswz(512 + mm, i0 + ic, 8)] = o4;
        }
    } else if (blk < 52) {
        // B2 cols [0,256) = target_w
        int base = (blk - 36) * 4096;
        #pragma unroll
        for (int k = 0; k < 4; ++k) {
            int e = base + k * 1024 + tid * 4;
            int o = e >> 8, c = e & 255;
            float4 v = *(const float4*)(target_w + e);
            ushort4 o4;
            o4.x = f2bf(v.x); o4.y = f2bf(v.y); o4.z = f2bf(v.z); o4.w = f2bf(v.w);
            *(ushort4*)&B2p[bswz(o, c, 11)] = o4;
        }
    } else if (blk < 56) {
        // B2 cols [256,320) = fcwe_w
        int base = (blk - 52) * 4096;
        #pragma unroll
        for (int k = 0; k < 4; ++k) {
            int e = base + k * 1024 + tid * 4;
            int o = e >> 6, m = e & 63;
            float4 v = *(const float4*)(fcwe_w + e);
            ushort4 o4;
            o4.x = f2bf(v.x); o4.y = f2bf(v.y); o4.z = f2bf(v.z); o4.w = f2bf(v.w);
            *(ushort4*)&B2p[bswz(o, 256 + m, 11)] = o4;
        }
    } else {
        // B2 tail per output o: cols [320,328)=fcbp_w, 328=fcwe_b, 329=bias, rest 0
        int o = tid;
        float4 p0 = *(const float4*)(fcbp_w + (size_t)o * 8);
        float4 p1 = *(const float4*)(fcbp_w + (size_t)o * 8 + 4);
        float pw[8] = {p0.x, p0.y, p0.z, p0.w, p1.x, p1.y, p1.z, p1.w};
        #pragma unroll
        for (int j = 0; j < 8; ++j)
            B2p[bswz(o, 320 + j, 11)] = f2bf(pw[j]);
        B2p[bswz(o, 328, 11)] = f2bf(fcwe_b[o]);
        float bc = target_b[o] + fcbp_b[o] + fcbi_b[o]
                 + index[0] * fcbi_w[o * 4]     + index[1] * fcbi_w[o * 4 + 1]
                 + index[2] * fcbi_w[o * 4 + 2] + index[3] * fcbi_w[o * 4 + 3];
        B2p[bswz(o, 329, 11)] = f2bf(bc);
        for (int z = 330; z < K2; ++z) B2p[bswz(o, z, 11)] = 0;
    }
}

// ---- main: per 32-sample strip: gemm1 row-strip + in-register fold + gemm2 ----
__global__ __launch_bounds__(256) void main_kernel(
    const float* __restrict__ x,             // [2048][256]
    const float* __restrict__ h,             // [2048][8]
    const unsigned short* __restrict__ Bbp,  // swizzled [36*8][64][8]
    const unsigned short* __restrict__ B2p,  // swizzled [16*11][64][8]
    float* __restrict__ out)                 // [2048][256]
{
    __shared__ unsigned short As[32 * LDA2S];   // 23040 B  A-panel [x|t|h|sx|1|0]
    __shared__ float T[32][68];                 // 8704 B   t accumulator (f32)
    __shared__ float Hs[32][8];                 // h staging
    __shared__ float red[32][8];                // sx partials

    const int tid = threadIdx.x, lane = tid & 63, w = tid >> 6;
    const int col = lane & 15, quad = lane >> 4;
    const int b0 = blockIdx.x * 32;

    // stage As x-cols [0,256): fp32 -> bf16
    #pragma unroll
    for (int it = 0; it < 8; ++it) {
        int idx = it * 256 + tid;
        int r = idx >> 6, c = (idx & 63) * 4;
        float4 v = *(const float4*)(x + (size_t)(b0 + r) * CIN + c);
        ushort4 o4;
        o4.x = f2bf(v.x); o4.y = f2bf(v.y); o4.z = f2bf(v.z); o4.w = f2bf(v.w);
        *(ushort4*)&As[r * LDA2S + c] = o4;
    }
    // h: LDS f32 copy + A-panel cols [320,328)
    {
        int s = tid >> 3, p = tid & 7;
        float hv = h[(size_t)(b0 + s) * NP + p];
        Hs[s][p] = hv;
        As[s * LDA2S + 320 + p] = f2bf(hv);
    }
    // sx partials (fp32 from global x)
    {
        int s = tid >> 3, seg = tid & 7;
        const float* xr = x + (size_t)(b0 + s) * CIN + seg * 32;
        float p = 0.f;
        #pragma unroll
        for (int k = 0; k < 8; ++k) {
            float4 v = *(const float4*)(xr + k * 4);
            p += v.x + v.y + v.z + v.w;
        }
        red[s][seg] = p;
    }
    // zero cols [330,352)
    for (int idx = tid; idx < 32 * 22; idx += 256) {
        int s = idx / 22, c = 330 + idx % 22;
        As[s * LDA2S + c] = 0;
    }
    __syncthreads();

    // ---------------- gemm1 row-strip + fold ----------------
    // wave w owns m in [16w,16w+16): p-tiles nt=8w..8w+7 and c-tile nt=32+w.
    float hw[2][4];
    #pragma unroll
    for (int g = 0; g < 2; ++g)
        #pragma unroll
        for (int r = 0; r < 4; ++r)
            hw[g][r] = Hs[g * 16 + quad * 4 + r][lane & 7];

    // c-tile first: initializes T[s][16w..16w+16)
    {
        const int nt = 32 + w;
        floatx4 acc0 = {0,0,0,0}, acc1 = {0,0,0,0};
        short8 bfr[8];
        #pragma unroll
        for (int kt = 0; kt < 8; ++kt)
            bfr[kt] = *(const short8*)&Bbp[(size_t)(nt * 8 + kt) * 512 + lane * 8];
        #pragma unroll
        for (int kt = 0; kt < 8; ++kt) {
            short8 af0 = *(const short8*)&As[(col) * LDA2S + kt * 32 + quad * 8];
            short8 af1 = *(const short8*)&As[(16 + col) * LDA2S + kt * 32 + quad * 8];
            acc0 = __builtin_amdgcn_mfma_f32_16x16x32_bf16(af0, bfr[kt], acc0, 0, 0, 0);
            acc1 = __builtin_amdgcn_mfma_f32_16x16x32_bf16(af1, bfr[kt], acc1, 0, 0, 0);
        }
        #pragma unroll
        for (int r = 0; r < 4; ++r) {
            T[quad * 4 + r][16 * w + col]      = acc0[r];
            T[16 + quad * 4 + r][16 * w + col] = acc1[r];
        }
    }
    // p-tiles: G-tile in registers, fold into T via 8-lane butterfly
    for (int j = 0; j < 8; ++j) {
        const int nt = 8 * w + j;
        floatx4 acc0 = {0,0,0,0}, acc1 = {0,0,0,0};
        short8 bfr[8];
        #pragma unroll
        for (int kt = 0; kt < 8; ++kt)
            bfr[kt] = *(const short8*)&Bbp[(size_t)(nt * 8 + kt) * 512 + lane * 8];
        #pragma unroll
        for (int kt = 0; kt < 8; ++kt) {
            short8 af0 = *(const short8*)&As[(col) * LDA2S + kt * 32 + quad * 8];
            short8 af1 = *(const short8*)&As[(16 + col) * LDA2S + kt * 32 + quad * 8];
            acc0 = __builtin_amdgcn_mfma_f32_16x16x32_bf16(af0, bfr[kt], acc0, 0, 0, 0);
            acc1 = __builtin_amdgcn_mfma_f32_16x16x32_bf16(af1, bfr[kt], acc1, 0, 0, 0);
        }
        // fold: t[s][2nt+b] += sum_p h[s][p]*G[s][16nt+8b+p]; b=(lane>>3)&1, p=lane&7
        const int mcol = 2 * nt + ((lane >> 3) & 1);
        #pragma unroll
        for (int g = 0; g < 2; ++g) {
            #pragma unroll
            for (int r = 0; r < 4; ++r) {
                float tmp = (g ? acc1[r] : acc0[r]) * hw[g][r];
                tmp += __shfl_xor(tmp, 1, 64);
                tmp += __shfl_xor(tmp, 2, 64);
                tmp += __shfl_xor(tmp, 4, 64);
                if ((lane & 7) == 0)
                    T[g * 16 + quad * 4 + r][mcol] += tmp;
            }
        }
    }
    __syncthreads();

    // t -> A-panel cols [256,320) (bf16)
    {
        int s = tid >> 3, mg = tid & 7;
        ushort4 t0, t1;
        t0.x = f2bf(T[s][mg * 8 + 0]); t0.y = f2bf(T[s][mg * 8 + 1]);
        t0.z = f2bf(T[s][mg * 8 + 2]); t0.w = f2bf(T[s][mg * 8 + 3]);
        t1.x = f2bf(T[s][mg * 8 + 4]); t1.y = f2bf(T[s][mg * 8 + 5]);
        t1.z = f2bf(T[s][mg * 8 + 6]); t1.w = f2bf(T[s][mg * 8 + 7]);
        *(ushort4*)&As[s * LDA2S + 256 + mg * 8]     = t0;
        *(ushort4*)&As[s * LDA2S + 256 + mg * 8 + 4] = t1;
    }
    // sx + ones into cols 328/329
    if (tid < 32) {
        float s = red[tid][0] + red[tid][1] + red[tid][2] + red[tid][3]
                + red[tid][4] + red[tid][5] + red[tid][6] + red[tid][7];
        As[tid * LDA2S + 328] = f2bf(s);
        As[tid * LDA2S + 329] = 0x3F80;   // 1.0 bf16
    }
    __syncthreads();

    // ---------------- gemm2: out = Apanel @ B2^T ----------------
    #pragma unroll
    for (int q = 0; q < 4; ++q) {
        const int nt2 = w * 4 + q;
        floatx4 acc0 = {0,0,0,0}, acc1 = {0,0,0,0};
        short8 bfr[11];
        #pragma unroll
        for (int kt = 0; kt < 11; ++kt)
            bfr[kt] = *(const short8*)&B2p[(size_t)(nt2 * 11 + kt) * 512 + lane * 8];
        #pragma unroll
        for (int kt = 0; kt < 11; ++kt) {
            short8 af0 = *(const short8*)&As[(col) * LDA2S + kt * 32 + quad * 8];
            short8 af1 = *(const short8*)&As[(16 + col) * LDA2S + kt * 32 + quad * 8];
            acc0 = __builtin_amdgcn_mfma_f32_16x16x32_bf16(af0, bfr[kt], acc0, 0, 0, 0);
            acc1 = __builtin_amdgcn_mfma_f32_16x16x32_bf16(af1, bfr[kt], acc1, 0, 0, 0);
        }
        #pragma unroll
        for (int r = 0; r < 4; ++r) {
            out[(size_t)(b0 + quad * 4 + r) * COUT + nt2 * 16 + col]      = acc0[r];
            out[(size_t)(b0 + 16 + quad * 4 + r) * COUT + nt2 * 16 + col] = acc1[r];
        }
    }
}

extern "C" void kernel_launch(void* const* d_in, const int* in_sizes, int n_in,
                              void* d_out, int out_size, void* d_ws, size_t ws_size,
                              hipStream_t stream) {
    const float* x        = (const float*)d_in[0];
    const float* h        = (const float*)d_in[1];
    const float* index    = (const float*)d_in[2];
    const float* target_w = (const float*)d_in[3];
    const float* target_b = (const float*)d_in[4];
    const float* fcwp_w   = (const float*)d_in[5];
    const float* fcwp_b   = (const float*)d_in[6];
    const float* fcwi_w   = (const float*)d_in[7];
    const float* fcwi_b   = (const float*)d_in[8];
    const float* fcwe_w   = (const float*)d_in[9];
    const float* fcwe_b   = (const float*)d_in[10];
    const float* fcbp_w   = (const float*)d_in[11];
    const float* fcbp_b   = (const float*)d_in[12];
    const float* fcbi_w   = (const float*)d_in[13];
    const float* fcbi_w2  = nullptr; (void)fcbi_w2;
    const float* fcbi_b   = (const float*)d_in[14];
    float* out = (float*)d_out;

    char* ws = (char*)d_ws;
    unsigned short* Bbp = (unsigned short*)ws;              // 36*8*512*2 = 294912
    unsigned short* B2p = (unsigned short*)(ws + 294912);   // 16*11*512*2 = 180224

    setup_kernel<<<57, 256, 0, stream>>>(
        index, fcwp_w, fcwp_b, fcwi_w, fcwi_b,
        target_w, target_b, fcwe_w, fcwe_b,
        fcbp_w, fcbp_b, fcbi_w, fcbi_b, Bbp, B2p);

    main_kernel<<<B_TOT / 32, 256, 0, stream>>>(x, h, Bbp, B2p, out);
}